// Round 2
// baseline (463.988 us; speedup 1.0000x reference)
//
#include <hip/hip_runtime.h>

#define NUM_BEAM 24
#define NUM_BIN  257
#define NUM_CH   8
#define N_FRAMES 16384
#define PAIRS    129   // ceil(257/2) bin-pairs per frame (last pair is partial)

// plain clang vector types -- accepted by __builtin_nontemporal_*
typedef float f4 __attribute__((ext_vector_type(4)));
typedef float f2 __attribute__((ext_vector_type(2)));

__device__ __forceinline__ float dot8(const f4& u0, const f4& u1,
                                      const f4& v0, const f4& v1) {
    return u0[0] * v0[0] + u0[1] * v0[1] + u0[2] * v0[2] + u0[3] * v0[3] +
           u1[0] * v1[0] + u1[1] * v1[1] + u1[2] * v1[2] + u1[3] * v1[3];
}

// input:   (F, 2, NUM_BIN, NUM_CH) f32   -- streamed, read exactly once (NT loads)
// W:       (NUM_BEAM, 2, NUM_BIN, NUM_CH) f32 -- 394 KB, L2-resident (normal loads)
// beam_id: (F,) int32
// out:     (F, 2, NUM_BIN, 1) f32        -- streamed, write-once (NT stores)
__global__ __launch_bounds__(256) void Beamformor_89653147336805_kernel(
    const float* __restrict__ input,
    const float* __restrict__ W,
    const int*   __restrict__ beam_id,
    float*       __restrict__ out)
{
    const int total = N_FRAMES * PAIRS;
    int idx = blockIdx.x * blockDim.x + threadIdx.x;
    if (idx >= total) return;

    int f  = idx / PAIRS;            // magic-mul
    int p  = idx - f * PAIRS;
    int b0 = p * 2;
    const bool full = (b0 + 1 < NUM_BIN);
    int b1 = full ? b0 + 1 : b0;     // clamp: tail pair re-reads bin 256, no OOB

    const int beam  = beam_id[f];
    const int plane = NUM_BIN * NUM_CH;                 // 2056 floats
    const float* xf = input + (size_t)f    * (2 * plane);
    const float* wf = W     + (size_t)beam * (2 * plane);

    const f4* xr0p = (const f4*)(xf +         b0 * NUM_CH);
    const f4* xi0p = (const f4*)(xf + plane + b0 * NUM_CH);
    const f4* xr1p = (const f4*)(xf +         b1 * NUM_CH);
    const f4* xi1p = (const f4*)(xf + plane + b1 * NUM_CH);
    const f4* wr0p = (const f4*)(wf +         b0 * NUM_CH);
    const f4* wi0p = (const f4*)(wf + plane + b0 * NUM_CH);
    const f4* wr1p = (const f4*)(wf +         b1 * NUM_CH);
    const f4* wi1p = (const f4*)(wf + plane + b1 * NUM_CH);

    // Issue all 16 loads up front; input via NT (read-once, don't pollute L2),
    // W via normal loads (keep resident in L2).
    f4 xr0a = __builtin_nontemporal_load(xr0p);
    f4 xr0b = __builtin_nontemporal_load(xr0p + 1);
    f4 xi0a = __builtin_nontemporal_load(xi0p);
    f4 xi0b = __builtin_nontemporal_load(xi0p + 1);
    f4 xr1a = __builtin_nontemporal_load(xr1p);
    f4 xr1b = __builtin_nontemporal_load(xr1p + 1);
    f4 xi1a = __builtin_nontemporal_load(xi1p);
    f4 xi1b = __builtin_nontemporal_load(xi1p + 1);
    f4 wr0a = wr0p[0], wr0b = wr0p[1];
    f4 wi0a = wi0p[0], wi0b = wi0p[1];
    f4 wr1a = wr1p[0], wr1b = wr1p[1];
    f4 wi1a = wi1p[0], wi1b = wi1p[1];

    // out_r = sum(xr*wr + xi*wi); out_i = sum(xi*wr - xr*wi)
    float r0 = dot8(xr0a, xr0b, wr0a, wr0b) + dot8(xi0a, xi0b, wi0a, wi0b);
    float i0 = dot8(xi0a, xi0b, wr0a, wr0b) - dot8(xr0a, xr0b, wi0a, wi0b);
    float r1 = dot8(xr1a, xr1b, wr1a, wr1b) + dot8(xi1a, xi1b, wi1a, wi1b);
    float i1 = dot8(xi1a, xi1b, wr1a, wr1b) - dot8(xr1a, xr1b, wi1a, wi1b);

    // out layout: (F, 2, NUM_BIN, 1) -> f*514 + plane_sel*257 + b
    float* o = out + (size_t)f * (2 * NUM_BIN);
    if (full) {
        // o + b0: f*514 even, b0 even -> 8B aligned, f2 OK
        f2 rr; rr[0] = r0; rr[1] = r1;
        __builtin_nontemporal_store(rr, (f2*)(o + b0));
        // imag row starts at odd offset 257 -> stays scalar (4B aligned only)
        __builtin_nontemporal_store(i0, o + NUM_BIN + b0);
        __builtin_nontemporal_store(i1, o + NUM_BIN + b1);
    } else {
        __builtin_nontemporal_store(r0, o + b0);
        __builtin_nontemporal_store(i0, o + NUM_BIN + b0);
    }
}

extern "C" void kernel_launch(void* const* d_in, const int* in_sizes, int n_in,
                              void* d_out, int out_size, void* d_ws, size_t ws_size,
                              hipStream_t stream) {
    const float* input   = (const float*)d_in[0];
    const float* W       = (const float*)d_in[1];
    const int*   beam_id = (const int*)d_in[2];
    float* out = (float*)d_out;

    const int total = N_FRAMES * PAIRS;              // 2,113,536
    const int block = 256;
    const int grid  = (total + block - 1) / block;   // 8256

    Beamformor_89653147336805_kernel<<<grid, block, 0, stream>>>(input, W, beam_id, out);
}

// Round 3
// 370.156 us; speedup vs baseline: 1.2535x; 1.2535x over previous
//
#include <hip/hip_runtime.h>

#define NUM_BEAM 24
#define NUM_BIN  257
#define NUM_CH   8
#define N_FRAMES 16384

// input:   (F, 2, NUM_BIN, NUM_CH) f32
// W:       (NUM_BEAM, 2, NUM_BIN, NUM_CH) f32
// beam_id: (F,) int
// out:     (F, 2, NUM_BIN, 1) f32
//
// One thread per (frame, bin). Wave-coalesced 32B/lane loads; W (394 KB) is
// L2/L3-resident via the normal cached path. NOTE: do NOT use
// __builtin_nontemporal_load here — measured 3.5x kernel regression on gfx950
// (L2 bypass -> latency-bound at 31% HBM, 43% over-fetch). Round-2 evidence.
__global__ __launch_bounds__(256) void Beamformor_89653147336805_kernel(
    const float* __restrict__ input,
    const float* __restrict__ W,
    const int*   __restrict__ beam_id,
    float*       __restrict__ out)
{
    const int total = N_FRAMES * NUM_BIN;
    int idx = blockIdx.x * blockDim.x + threadIdx.x;
    if (idx >= total) return;

    int f = idx / NUM_BIN;           // compiler emits magic-mul for /257
    int b = idx - f * NUM_BIN;

    int beam = beam_id[f];

    const size_t f_base = (size_t)f    * (2 * NUM_BIN * NUM_CH);
    const size_t w_base = (size_t)beam * (2 * NUM_BIN * NUM_CH);
    const int    plane  = NUM_BIN * NUM_CH;   // 2056 floats
    const int    boff   = b * NUM_CH;         // 32B-aligned

    const float4* xr = (const float4*)(input + f_base + boff);
    const float4* xi = (const float4*)(input + f_base + plane + boff);
    const float4* wr = (const float4*)(W + w_base + boff);
    const float4* wi = (const float4*)(W + w_base + plane + boff);

    float4 xr0 = xr[0], xr1 = xr[1];
    float4 xi0 = xi[0], xi1 = xi[1];
    float4 wr0 = wr[0], wr1 = wr[1];
    float4 wi0 = wi[0], wi1 = wi[1];

    // out_r = sum(xr*wr + xi*wi); out_i = sum(xi*wr - xr*wi)
    float out_r =
        xr0.x * wr0.x + xr0.y * wr0.y + xr0.z * wr0.z + xr0.w * wr0.w +
        xr1.x * wr1.x + xr1.y * wr1.y + xr1.z * wr1.z + xr1.w * wr1.w +
        xi0.x * wi0.x + xi0.y * wi0.y + xi0.z * wi0.z + xi0.w * wi0.w +
        xi1.x * wi1.x + xi1.y * wi1.y + xi1.z * wi1.z + xi1.w * wi1.w;

    float out_i =
        xi0.x * wr0.x + xi0.y * wr0.y + xi0.z * wr0.z + xi0.w * wr0.w +
        xi1.x * wr1.x + xi1.y * wr1.y + xi1.z * wr1.z + xi1.w * wr1.w -
        xr0.x * wi0.x - xr0.y * wi0.y - xr0.z * wi0.z - xr0.w * wi0.w -
        xr1.x * wi1.x - xr1.y * wi1.y - xr1.z * wi1.z - xr1.w * wi1.w;

    // out layout: (F, 2, NUM_BIN, 1) -> f*2*257 + p*257 + b
    size_t o_base = (size_t)f * (2 * NUM_BIN) + b;
    out[o_base]           = out_r;
    out[o_base + NUM_BIN] = out_i;
}

extern "C" void kernel_launch(void* const* d_in, const int* in_sizes, int n_in,
                              void* d_out, int out_size, void* d_ws, size_t ws_size,
                              hipStream_t stream) {
    const float* input   = (const float*)d_in[0];
    const float* W       = (const float*)d_in[1];
    const int*   beam_id = (const int*)d_in[2];
    float* out = (float*)d_out;

    const int total  = N_FRAMES * NUM_BIN;           // 4,210,688
    const int block  = 256;
    const int grid   = (total + block - 1) / block;  // 16448

    Beamformor_89653147336805_kernel<<<grid, block, 0, stream>>>(input, W, beam_id, out);
}